// Round 1
// baseline (160.026 us; speedup 1.0000x reference)
//
#include <hip/hip_runtime.h>
#include <cstdint>

// IDCT (DCT-III) of 4096x4096 fp32 via even/odd decimation + int8 MFMA GEMMs.
//   y_k       = E_k + O_k          (k < N/2)
//   y_{N-1-k} = E_k - O_k
//   E_k = sum_m we_m x[2m]   cos(pi*m*(2k+1)/N)      (we_0=1, else 2)
//   O_k = sum_m 2    x[2m+1] cos(pi*(2m+1)*(2k+1)/(2N))
// R6: T3 "minimum 2-phase" pipeline on the fused GEMM: double-buffered LDS
// (128 KB), stage tile t+1 BEFORE computing tile t, single counted-drain
// vmcnt(0) + ONE raw s_barrier per K-step (was: 2 __syncthreads with full
// drain and zero in-block overlap). 512 threads / 8 waves so the 1-block/CU
// occupancy still gives 2 waves/SIMD. Proven BK=128 XOR-(r&7) swizzle and
// 16x16x64 i8 MFMA fragment geometry unchanged.

#define NN 4096
#define HH 2048   // N/2 = K-dim of the split GEMMs and half-spectrum width
#define BM 128
#define BN 128
#define BK 128    // i8 elems per K-step (128 B rows -> proven swizzle geometry)
#define NT (HH / BK)   // 16 K-steps

typedef int i32x4 __attribute__((ext_vector_type(4)));
typedef int i32x2 __attribute__((ext_vector_type(2)));

// async global->LDS, 16B per lane (HW: LDS dest = wave-uniform base + lane*16)
__device__ __forceinline__ void async_copy16(void* lds_base, const void* gptr) {
    __builtin_amdgcn_global_load_lds(
        (const __attribute__((address_space(1))) unsigned int*)gptr,
        (__attribute__((address_space(3))) unsigned int*)lds_base,
        16, 0, 0);
}

__device__ __forceinline__ int pack4(int q0, int q1, int q2, int q3) {
    return (q0 & 255) | ((q1 & 255) << 8) | ((q2 & 255) << 16) | ((q3 & 255) << 24);
}

// ---- prep ----
// blocks 0..4095     : quantize row b of X into Ae (even cols) + Ao (odd cols),
//                      per-row-per-parity scales se[b], so[b]
// blocks 4096..6143  : CE row k  (CE[k][m] = we_m cos(pi*m*(2k+1)/N))
// blocks 6144..8191  : CO row k  (CO[k][m] = 2 cos(pi*(2m+1)*(2k+1)/2N))
__global__ __launch_bounds__(256) void prep_i8(const float* __restrict__ x,
                                               signed char* __restrict__ Ae,
                                               signed char* __restrict__ Ao,
                                               signed char* __restrict__ CEm,
                                               signed char* __restrict__ COm,
                                               float* __restrict__ se,
                                               float* __restrict__ so) {
    const int b = blockIdx.x;
    const int t = threadIdx.x;
    const float s = 3.834951969714103e-4f;   // pi / 8192

    if (b < 4096) {
        __shared__ float wmaxe[4], wmaxo[4];
        const float* xr = x + (size_t)b * NN;
        float v[16];                          // elements n = t*16 .. t*16+15
#pragma unroll
        for (int j = 0; j < 4; ++j) {
            float4 f = ((const float4*)xr)[t * 4 + j];
            v[j * 4 + 0] = f.x; v[j * 4 + 1] = f.y;
            v[j * 4 + 2] = f.z; v[j * 4 + 3] = f.w;
        }
        float emax = 1e-30f, omax = 1e-30f;
#pragma unroll
        for (int i = 0; i < 8; ++i) {
            emax = fmaxf(emax, __builtin_fabsf(v[2 * i]));
            omax = fmaxf(omax, __builtin_fabsf(v[2 * i + 1]));
        }
        // 64-lane butterfly reduce (no barrier)
#pragma unroll
        for (int m = 1; m < 64; m <<= 1) {
            emax = fmaxf(emax, __shfl_xor(emax, m));
            omax = fmaxf(omax, __shfl_xor(omax, m));
        }
        const int wv = t >> 6;
        if ((t & 63) == 0) { wmaxe[wv] = emax; wmaxo[wv] = omax; }
        __syncthreads();
        const float rmax_e = fmaxf(fmaxf(wmaxe[0], wmaxe[1]), fmaxf(wmaxe[2], wmaxe[3]));
        const float rmax_o = fmaxf(fmaxf(wmaxo[0], wmaxo[1]), fmaxf(wmaxo[2], wmaxo[3]));
        const float inv_e = 127.0f / rmax_e, inv_o = 127.0f / rmax_o;
        int qe[8], qo[8];
#pragma unroll
        for (int i = 0; i < 8; ++i) {
            qe[i] = (int)rintf(v[2 * i] * inv_e);
            qo[i] = (int)rintf(v[2 * i + 1] * inv_o);
        }
        i32x2 oe, oo;
        oe[0] = pack4(qe[0], qe[1], qe[2], qe[3]);
        oe[1] = pack4(qe[4], qe[5], qe[6], qe[7]);
        oo[0] = pack4(qo[0], qo[1], qo[2], qo[3]);
        oo[1] = pack4(qo[4], qo[5], qo[6], qo[7]);
        ((i32x2*)(Ae + (size_t)b * HH))[t] = oe;   // m = t*8 .. t*8+7
        ((i32x2*)(Ao + (size_t)b * HH))[t] = oo;
        if (t == 0) {
            se[b] = rmax_e * (1.0f / 127.0f);
            so[b] = rmax_o * (1.0f / 127.0f);
        }
    } else if (b < 6144) {
        const int k = b - 4096;
        const int twok1 = 2 * k + 1;
        int q[8];
#pragma unroll
        for (int i = 0; i < 8; ++i) {
            int m = t * 8 + i;
            int p = (2 * m * twok1) & 16383;            // angle = p * pi/8192
            float w = (m == 0) ? 1.0f : 2.0f;
            q[i] = (int)rintf(w * __cosf((float)p * s) * 63.5f);  // scale 2/127
        }
        i32x2 o;
        o[0] = pack4(q[0], q[1], q[2], q[3]);
        o[1] = pack4(q[4], q[5], q[6], q[7]);
        ((i32x2*)(CEm + (size_t)k * HH))[t] = o;
    } else {
        const int k = b - 6144;
        const int twok1 = 2 * k + 1;
        int q[8];
#pragma unroll
        for (int i = 0; i < 8; ++i) {
            int m = t * 8 + i;
            int p = ((2 * m + 1) * twok1) & 16383;
            q[i] = (int)rintf(__cosf((float)p * s) * 127.0f);     // 2*cos, scale 2/127
        }
        i32x2 o;
        o[0] = pack4(q[0], q[1], q[2], q[3]);
        o[1] = pack4(q[4], q[5], q[6], q[7]);
        ((i32x2*)(COm + (size_t)k * HH))[t] = o;
    }
}

// ---- fused split GEMM, pipelined: accE = Ae*CE^T and accO = Ao*CO^T ----
// 128x128 tile, BK=128, 8 waves (2M x 4N, 64x32 per wave per branch).
// Double-buffered LDS (128 KB), T3 minimum-2-phase schedule:
//   STAGE(next) ; COMPUTE(cur) ; vmcnt(0)+lgkmcnt(0) ; s_barrier
// One barrier per K-step; next-tile loads fly during the MFMA burst.
// XOR-swizzled LDS (granule g of row r at g^(r&7)) -> 0 bank conflicts.
__global__ __launch_bounds__(512, 2) void idct_gemm2(const signed char* __restrict__ Ae,
                                                     const signed char* __restrict__ Ao,
                                                     const signed char* __restrict__ CEm,
                                                     const signed char* __restrict__ COm,
                                                     const float* __restrict__ se,
                                                     const float* __restrict__ so,
                                                     float* __restrict__ C) {
    __shared__ __align__(16) signed char sAe[2][BM * BK];   // 2 x 16 KB
    __shared__ __align__(16) signed char sAo[2][BM * BK];   // 2 x 16 KB
    __shared__ __align__(16) signed char sCE[2][BN * BK];   // 2 x 16 KB
    __shared__ __align__(16) signed char sCO[2][BN * BK];   // 2 x 16 KB  (128 KB)

    const int tid  = threadIdx.x;
    const int wave = tid >> 6;          // 0..7
    const int lane = tid & 63;
    const int waveM = wave >> 2;        // 0..1 -> 64-row band
    const int waveN = wave & 3;         // 0..3 -> 32-col band

    const int rowBase = blockIdx.y * BM;        // output rows
    const int colBase = blockIdx.x * BN;        // half-spectrum cols k in [0,2048)

    i32x4 accE[4][2] = {};
    i32x4 accO[4][2] = {};

    // staging: chunk = 1 KB = 8 rows x 8 granules(16B); 16 chunks per matrix,
    // 2 chunks per wave per matrix (8 waves) -> 8 async issues/thread/K-step
    const int srow  = lane >> 3;              // row within chunk (== r&7)
    const int sgran = lane & 7;               // physical granule this lane fills
    const int ggcol = (sgran ^ srow) * 16;    // swizzle baked into global col (bytes)
    const int rmod  = lane & 7;
    const int quad  = lane >> 4;
    const int ck0   = wave * 2;               // first chunk owned by this wave

    const size_t aRow = (size_t)(rowBase + ck0 * 8 + srow) * HH + ggcol;
    const size_t bRow = (size_t)(colBase + ck0 * 8 + srow) * HH + ggcol;

#define STAGE(BUF, K0)                                                        \
    do {                                                                      \
        _Pragma("unroll")                                                     \
        for (int j = 0; j < 2; ++j) {                                         \
            size_t aoff = aRow + (size_t)j * 8 * HH + (size_t)(K0);           \
            size_t boff = bRow + (size_t)j * 8 * HH + (size_t)(K0);           \
            async_copy16(&sAe[BUF][(ck0 + j) * 1024], Ae + aoff);             \
            async_copy16(&sAo[BUF][(ck0 + j) * 1024], Ao + aoff);             \
            async_copy16(&sCE[BUF][(ck0 + j) * 1024], CEm + boff);            \
            async_copy16(&sCO[BUF][(ck0 + j) * 1024], COm + boff);            \
        }                                                                     \
    } while (0)

#define COMPUTE(BUF)                                                          \
    do {                                                                      \
        _Pragma("unroll")                                                     \
        for (int kk = 0; kk < 2; ++kk) {                                      \
            const int poff = ((kk * 4 + quad) ^ rmod) * 16;                   \
            i32x4 af[4], bfr[2];                                              \
            _Pragma("unroll")                                                 \
            for (int mi = 0; mi < 4; ++mi)                                    \
                af[mi] = *(const i32x4*)&sAe[BUF][(waveM * 64 + mi * 16 + (lane & 15)) * BK + poff]; \
            _Pragma("unroll")                                                 \
            for (int ni = 0; ni < 2; ++ni)                                    \
                bfr[ni] = *(const i32x4*)&sCE[BUF][(waveN * 32 + ni * 16 + (lane & 15)) * BK + poff]; \
            __builtin_amdgcn_s_setprio(1);                                    \
            _Pragma("unroll")                                                 \
            for (int mi = 0; mi < 4; ++mi)                                    \
                _Pragma("unroll")                                             \
                for (int ni = 0; ni < 2; ++ni)                                \
                    accE[mi][ni] = __builtin_amdgcn_mfma_i32_16x16x64_i8(     \
                        af[mi], bfr[ni], accE[mi][ni], 0, 0, 0);              \
            __builtin_amdgcn_s_setprio(0);                                    \
            _Pragma("unroll")                                                 \
            for (int mi = 0; mi < 4; ++mi)                                    \
                af[mi] = *(const i32x4*)&sAo[BUF][(waveM * 64 + mi * 16 + (lane & 15)) * BK + poff]; \
            _Pragma("unroll")                                                 \
            for (int ni = 0; ni < 2; ++ni)                                    \
                bfr[ni] = *(const i32x4*)&sCO[BUF][(waveN * 32 + ni * 16 + (lane & 15)) * BK + poff]; \
            __builtin_amdgcn_s_setprio(1);                                    \
            _Pragma("unroll")                                                 \
            for (int mi = 0; mi < 4; ++mi)                                    \
                _Pragma("unroll")                                             \
                for (int ni = 0; ni < 2; ++ni)                                \
                    accO[mi][ni] = __builtin_amdgcn_mfma_i32_16x16x64_i8(     \
                        af[mi], bfr[ni], accO[mi][ni], 0, 0, 0);              \
            __builtin_amdgcn_s_setprio(0);                                    \
        }                                                                     \
    } while (0)

    // prologue: fill buf0
    STAGE(0, 0);
    asm volatile("s_waitcnt vmcnt(0)" ::: "memory");
    __builtin_amdgcn_s_barrier();

    // main loop, unrolled x2 so buffer indices are compile-time constants
    // (lets alias analysis prove STAGE(buf^1) does not touch COMPUTE(buf))
#pragma unroll 1
    for (int t = 0; t < NT; t += 2) {
        STAGE(1, (t + 1) * BK);                   // next tile flies during MFMA
        COMPUTE(0);
        asm volatile("s_waitcnt vmcnt(0) lgkmcnt(0)" ::: "memory");
        __builtin_amdgcn_s_barrier();

        if (t + 2 < NT) STAGE(0, (t + 2) * BK);
        COMPUTE(1);
        asm volatile("s_waitcnt vmcnt(0) lgkmcnt(0)" ::: "memory");
        __builtin_amdgcn_s_barrier();
    }
#undef STAGE
#undef COMPUTE

    // epilogue: C/D layout col = lane&15, row = (lane>>4)*4 + reg; butterfly
    const float sB_s = 2.0f / 127.0f;
    const int mrow0 = rowBase + waveM * 64 + (lane >> 4) * 4;
    const int ncol0 = colBase + waveN * 32 + (lane & 15);
#pragma unroll
    for (int mi = 0; mi < 4; ++mi)
#pragma unroll
        for (int ni = 0; ni < 2; ++ni)
#pragma unroll
            for (int rg = 0; rg < 4; ++rg) {
                int rr = mrow0 + mi * 16 + rg;
                int cc = ncol0 + ni * 16;
                float e = (float)accE[mi][ni][rg] * (se[rr] * sB_s);
                float o = (float)accO[mi][ni][rg] * (so[rr] * sB_s);
                C[(size_t)rr * NN + cc] = e + o;
                C[(size_t)rr * NN + (NN - 1 - cc)] = e - o;
            }
}

// ---- fallback: direct O(N^2) eval (only if ws_size is too small) ----
__global__ __launch_bounds__(256) void idct_naive(const float* __restrict__ x,
                                                  float* __restrict__ out) {
    int row = blockIdx.x;
    __shared__ float sx[NN];
    for (int i = threadIdx.x; i < NN; i += 256) sx[i] = x[(size_t)row * NN + i];
    __syncthreads();
    const float s = 3.834951969714103e-4f;  // pi / 8192
    for (int k = threadIdx.x; k < NN; k += 256) {
        int twok1 = 2 * k + 1;
        float acc = sx[0];
        int p = 0;
        for (int n = 1; n < NN; ++n) {
            p += twok1; p &= 16383;
            acc += 2.0f * sx[n] * __cosf((float)p * s);
        }
        out[(size_t)row * NN + k] = acc;
    }
}

extern "C" void kernel_launch(void* const* d_in, const int* in_sizes, int n_in,
                              void* d_out, int out_size, void* d_ws, size_t ws_size,
                              hipStream_t stream) {
    const float* x = (const float*)d_in[0];
    float* out = (float*)d_out;

    const size_t eA = (size_t)NN * HH;          // 8 MB each for Ae/Ao
    const size_t eC = (size_t)HH * HH;          // 4 MB each for CE/CO
    const size_t need = 2 * eA + 2 * eC + 2 * NN * sizeof(float);

    if (ws_size >= need) {
        signed char* Ae = (signed char*)d_ws;
        signed char* Ao = Ae + eA;
        signed char* CEm = Ao + eA;
        signed char* COm = CEm + eC;
        float* se = (float*)(COm + eC);
        float* so = se + NN;

        prep_i8<<<8192, 256, 0, stream>>>(x, Ae, Ao, CEm, COm, se, so);

        dim3 grid(HH / BN, NN / BM);            // (16, 32) = 512 blocks
        idct_gemm2<<<grid, 512, 0, stream>>>(Ae, Ao, CEm, COm, se, so, out);
    } else {
        idct_naive<<<NN, 256, 0, stream>>>(x, out);
    }
}

// Round 2
// 153.641 us; speedup vs baseline: 1.0416x; 1.0416x over previous
//
#include <hip/hip_runtime.h>
#include <cstdint>

// IDCT (DCT-III) of 4096x4096 fp32 via even/odd decimation + int8 MFMA GEMMs.
//   y_k       = E_k + O_k          (k < N/2)
//   y_{N-1-k} = E_k - O_k
//   E_k = sum_m we_m x[2m]   cos(pi*m*(2k+1)/N)      (we_0=1, else 2)
//   O_k = sum_m 2    x[2m+1] cos(pi*(2m+1)*(2k+1)/(2N))
// R7: restore R5's 2-blocks/CU (256 thr, cross-block overlap = proven 27%
// MfmaUtil floor) AND add counted-vmcnt double-buffer pipeline (T4):
// BK=64 so dbuf fits 64 KB/block -> 2 blocks/CU in 128 KB LDS.
// Per K-step: STAGE(next); vmcnt(8) <- waits only for PREVIOUS stage, the
// fresh 8 loads stay in flight across the barrier; barrier; COMPUTE; barrier.
// BK=64 swizzle: phys granule = g ^ ((r>>1)&3) (row parity supplies the
// 3rd position bit; conflict-free per 8-lane ds_read_b128 phase).

#define NN 4096
#define HH 2048   // N/2 = K-dim of the split GEMMs and half-spectrum width
#define BM 128
#define BN 128
#define BK 64     // i8 elems per K-step; 64 B rows, 4 granules of 16 B
#define NT (HH / BK)   // 32 K-steps

typedef int i32x4 __attribute__((ext_vector_type(4)));
typedef int i32x2 __attribute__((ext_vector_type(2)));

// async global->LDS, 16B per lane (HW: LDS dest = wave-uniform base + lane*16)
__device__ __forceinline__ void async_copy16(void* lds_base, const void* gptr) {
    __builtin_amdgcn_global_load_lds(
        (const __attribute__((address_space(1))) unsigned int*)gptr,
        (__attribute__((address_space(3))) unsigned int*)lds_base,
        16, 0, 0);
}

__device__ __forceinline__ int pack4(int q0, int q1, int q2, int q3) {
    return (q0 & 255) | ((q1 & 255) << 8) | ((q2 & 255) << 16) | ((q3 & 255) << 24);
}

// ---- prep ---- (unchanged from R5)
__global__ __launch_bounds__(256) void prep_i8(const float* __restrict__ x,
                                               signed char* __restrict__ Ae,
                                               signed char* __restrict__ Ao,
                                               signed char* __restrict__ CEm,
                                               signed char* __restrict__ COm,
                                               float* __restrict__ se,
                                               float* __restrict__ so) {
    const int b = blockIdx.x;
    const int t = threadIdx.x;
    const float s = 3.834951969714103e-4f;   // pi / 8192

    if (b < 4096) {
        __shared__ float wmaxe[4], wmaxo[4];
        const float* xr = x + (size_t)b * NN;
        float v[16];                          // elements n = t*16 .. t*16+15
#pragma unroll
        for (int j = 0; j < 4; ++j) {
            float4 f = ((const float4*)xr)[t * 4 + j];
            v[j * 4 + 0] = f.x; v[j * 4 + 1] = f.y;
            v[j * 4 + 2] = f.z; v[j * 4 + 3] = f.w;
        }
        float emax = 1e-30f, omax = 1e-30f;
#pragma unroll
        for (int i = 0; i < 8; ++i) {
            emax = fmaxf(emax, __builtin_fabsf(v[2 * i]));
            omax = fmaxf(omax, __builtin_fabsf(v[2 * i + 1]));
        }
        // 64-lane butterfly reduce (no barrier)
#pragma unroll
        for (int m = 1; m < 64; m <<= 1) {
            emax = fmaxf(emax, __shfl_xor(emax, m));
            omax = fmaxf(omax, __shfl_xor(omax, m));
        }
        const int wv = t >> 6;
        if ((t & 63) == 0) { wmaxe[wv] = emax; wmaxo[wv] = omax; }
        __syncthreads();
        const float rmax_e = fmaxf(fmaxf(wmaxe[0], wmaxe[1]), fmaxf(wmaxe[2], wmaxe[3]));
        const float rmax_o = fmaxf(fmaxf(wmaxo[0], wmaxo[1]), fmaxf(wmaxo[2], wmaxo[3]));
        const float inv_e = 127.0f / rmax_e, inv_o = 127.0f / rmax_o;
        int qe[8], qo[8];
#pragma unroll
        for (int i = 0; i < 8; ++i) {
            qe[i] = (int)rintf(v[2 * i] * inv_e);
            qo[i] = (int)rintf(v[2 * i + 1] * inv_o);
        }
        i32x2 oe, oo;
        oe[0] = pack4(qe[0], qe[1], qe[2], qe[3]);
        oe[1] = pack4(qe[4], qe[5], qe[6], qe[7]);
        oo[0] = pack4(qo[0], qo[1], qo[2], qo[3]);
        oo[1] = pack4(qo[4], qo[5], qo[6], qo[7]);
        ((i32x2*)(Ae + (size_t)b * HH))[t] = oe;   // m = t*8 .. t*8+7
        ((i32x2*)(Ao + (size_t)b * HH))[t] = oo;
        if (t == 0) {
            se[b] = rmax_e * (1.0f / 127.0f);
            so[b] = rmax_o * (1.0f / 127.0f);
        }
    } else if (b < 6144) {
        const int k = b - 4096;
        const int twok1 = 2 * k + 1;
        int q[8];
#pragma unroll
        for (int i = 0; i < 8; ++i) {
            int m = t * 8 + i;
            int p = (2 * m * twok1) & 16383;            // angle = p * pi/8192
            float w = (m == 0) ? 1.0f : 2.0f;
            q[i] = (int)rintf(w * __cosf((float)p * s) * 63.5f);  // scale 2/127
        }
        i32x2 o;
        o[0] = pack4(q[0], q[1], q[2], q[3]);
        o[1] = pack4(q[4], q[5], q[6], q[7]);
        ((i32x2*)(CEm + (size_t)k * HH))[t] = o;
    } else {
        const int k = b - 6144;
        const int twok1 = 2 * k + 1;
        int q[8];
#pragma unroll
        for (int i = 0; i < 8; ++i) {
            int m = t * 8 + i;
            int p = ((2 * m + 1) * twok1) & 16383;
            q[i] = (int)rintf(__cosf((float)p * s) * 127.0f);     // 2*cos, scale 2/127
        }
        i32x2 o;
        o[0] = pack4(q[0], q[1], q[2], q[3]);
        o[1] = pack4(q[4], q[5], q[6], q[7]);
        ((i32x2*)(COm + (size_t)k * HH))[t] = o;
    }
}

// ---- fused split GEMM, counted-vmcnt pipelined ----
// 128x128 tile, BK=64, 4 waves 2x2 (R5 geometry), double-buffered LDS 64 KB.
// STAGE = 8 async_copy16/thread (4 matrices x 2 chunks); chunk = 1 KB =
// 16 rows x 4 granules. Swizzle: phys granule = g ^ ((r>>1)&3), applied on
// the pre-swizzled GLOBAL source and on the ds_read offset (rule 21).
__global__ __launch_bounds__(256, 2) void idct_gemm2(const signed char* __restrict__ Ae,
                                                     const signed char* __restrict__ Ao,
                                                     const signed char* __restrict__ CEm,
                                                     const signed char* __restrict__ COm,
                                                     const float* __restrict__ se,
                                                     const float* __restrict__ so,
                                                     float* __restrict__ C) {
    __shared__ __align__(16) signed char sAe[2][BM * BK];   // 2 x 8 KB
    __shared__ __align__(16) signed char sAo[2][BM * BK];   // 2 x 8 KB
    __shared__ __align__(16) signed char sCE[2][BN * BK];   // 2 x 8 KB
    __shared__ __align__(16) signed char sCO[2][BN * BK];   // 2 x 8 KB  (64 KB)

    const int tid  = threadIdx.x;
    const int wave = tid >> 6;          // 0..3
    const int lane = tid & 63;
    const int waveM = wave >> 1;        // 0..1 -> 64-row band
    const int waveN = wave & 1;         // 0..1 -> 64-col band

    const int rowBase = blockIdx.y * BM;        // output rows
    const int colBase = blockIdx.x * BN;        // half-spectrum cols k in [0,2048)

    i32x4 accE[4][4] = {};
    i32x4 accO[4][4] = {};

    // staging: chunk = 1 KB = 16 rows x 4 granules(16B); 8 chunks per matrix,
    // 2 chunks per wave per matrix (4 waves) -> 8 async issues/thread/K-step
    const int srow  = lane >> 2;              // row within chunk, 0..15
    const int sgran = lane & 3;               // physical granule this lane fills
    const int ggcol = (sgran ^ ((srow >> 1) & 3)) * 16;  // swizzle baked into global col
    const int quad  = lane >> 4;              // logical granule for MFMA reads
    const int fsw   = (lane >> 1) & 3;        // = (r>>1)&3 for the rows this lane reads
    const int poff  = (quad ^ fsw) * 16;      // swizzled byte offset within row
    const int ck0   = wave * 2;               // first chunk owned by this wave

    const size_t aRow = (size_t)(rowBase + ck0 * 16 + srow) * HH + ggcol;
    const size_t bRow = (size_t)(colBase + ck0 * 16 + srow) * HH + ggcol;

#define STAGE(BUF, K0)                                                        \
    do {                                                                      \
        _Pragma("unroll")                                                     \
        for (int j = 0; j < 2; ++j) {                                         \
            size_t aoff = aRow + (size_t)j * 16 * HH + (size_t)(K0);          \
            size_t boff = bRow + (size_t)j * 16 * HH + (size_t)(K0);          \
            async_copy16(&sAe[BUF][(ck0 + j) * 1024], Ae + aoff);             \
            async_copy16(&sAo[BUF][(ck0 + j) * 1024], Ao + aoff);             \
            async_copy16(&sCE[BUF][(ck0 + j) * 1024], CEm + boff);            \
            async_copy16(&sCO[BUF][(ck0 + j) * 1024], COm + boff);            \
        }                                                                     \
    } while (0)

#define COMPUTE(BUF)                                                          \
    do {                                                                      \
        i32x4 af[4], bfr[4];                                                  \
        _Pragma("unroll")                                                     \
        for (int mi = 0; mi < 4; ++mi)                                        \
            af[mi] = *(const i32x4*)&sAe[BUF][(waveM * 64 + mi * 16 + (lane & 15)) * BK + poff]; \
        _Pragma("unroll")                                                     \
        for (int ni = 0; ni < 4; ++ni)                                        \
            bfr[ni] = *(const i32x4*)&sCE[BUF][(waveN * 64 + ni * 16 + (lane & 15)) * BK + poff]; \
        __builtin_amdgcn_s_setprio(1);                                        \
        _Pragma("unroll")                                                     \
        for (int mi = 0; mi < 4; ++mi)                                        \
            _Pragma("unroll")                                                 \
            for (int ni = 0; ni < 4; ++ni)                                    \
                accE[mi][ni] = __builtin_amdgcn_mfma_i32_16x16x64_i8(         \
                    af[mi], bfr[ni], accE[mi][ni], 0, 0, 0);                  \
        __builtin_amdgcn_s_setprio(0);                                        \
        _Pragma("unroll")                                                     \
        for (int mi = 0; mi < 4; ++mi)                                        \
            af[mi] = *(const i32x4*)&sAo[BUF][(waveM * 64 + mi * 16 + (lane & 15)) * BK + poff]; \
        _Pragma("unroll")                                                     \
        for (int ni = 0; ni < 4; ++ni)                                        \
            bfr[ni] = *(const i32x4*)&sCO[BUF][(waveN * 64 + ni * 16 + (lane & 15)) * BK + poff]; \
        __builtin_amdgcn_s_setprio(1);                                        \
        _Pragma("unroll")                                                     \
        for (int mi = 0; mi < 4; ++mi)                                        \
            _Pragma("unroll")                                                 \
            for (int ni = 0; ni < 4; ++ni)                                    \
                accO[mi][ni] = __builtin_amdgcn_mfma_i32_16x16x64_i8(         \
                    af[mi], bfr[ni], accO[mi][ni], 0, 0, 0);                  \
        __builtin_amdgcn_s_setprio(0);                                        \
    } while (0)

    // prologue: fill buf0 (8 loads in flight)
    STAGE(0, 0);

    // main loop, unrolled x2 so buffer indices are compile-time constants.
    // vmcnt(8): the 8 loads just issued for the NEXT tile stay in flight
    // across the barrier; we only wait for the PREVIOUS stage's 8.
#pragma unroll 1
    for (int t = 0; t < NT - 2; t += 2) {
        STAGE(1, (t + 1) * BK);
        asm volatile("s_waitcnt vmcnt(8)" ::: "memory");
        __builtin_amdgcn_s_barrier();
        COMPUTE(0);
        __builtin_amdgcn_s_barrier();

        STAGE(0, (t + 2) * BK);
        asm volatile("s_waitcnt vmcnt(8)" ::: "memory");
        __builtin_amdgcn_s_barrier();
        COMPUTE(1);
        __builtin_amdgcn_s_barrier();
    }
    // tail: tile NT-2 (buf0) while staging the last tile, then tile NT-1 (buf1)
    STAGE(1, (NT - 1) * BK);
    asm volatile("s_waitcnt vmcnt(8)" ::: "memory");
    __builtin_amdgcn_s_barrier();
    COMPUTE(0);
    __builtin_amdgcn_s_barrier();

    asm volatile("s_waitcnt vmcnt(0)" ::: "memory");
    __builtin_amdgcn_s_barrier();
    COMPUTE(1);
#undef STAGE
#undef COMPUTE

    // epilogue: C/D layout col = lane&15, row = (lane>>4)*4 + reg; butterfly
    const float sB_s = 2.0f / 127.0f;
    const int mrow0 = rowBase + waveM * 64 + (lane >> 4) * 4;
    const int ncol0 = colBase + waveN * 64 + (lane & 15);
#pragma unroll
    for (int mi = 0; mi < 4; ++mi)
#pragma unroll
        for (int ni = 0; ni < 4; ++ni)
#pragma unroll
            for (int rg = 0; rg < 4; ++rg) {
                int rr = mrow0 + mi * 16 + rg;
                int cc = ncol0 + ni * 16;
                float e = (float)accE[mi][ni][rg] * (se[rr] * sB_s);
                float o = (float)accO[mi][ni][rg] * (so[rr] * sB_s);
                C[(size_t)rr * NN + cc] = e + o;
                C[(size_t)rr * NN + (NN - 1 - cc)] = e - o;
            }
}

// ---- fallback: direct O(N^2) eval (only if ws_size is too small) ----
__global__ __launch_bounds__(256) void idct_naive(const float* __restrict__ x,
                                                  float* __restrict__ out) {
    int row = blockIdx.x;
    __shared__ float sx[NN];
    for (int i = threadIdx.x; i < NN; i += 256) sx[i] = x[(size_t)row * NN + i];
    __syncthreads();
    const float s = 3.834951969714103e-4f;  // pi / 8192
    for (int k = threadIdx.x; k < NN; k += 256) {
        int twok1 = 2 * k + 1;
        float acc = sx[0];
        int p = 0;
        for (int n = 1; n < NN; ++n) {
            p += twok1; p &= 16383;
            acc += 2.0f * sx[n] * __cosf((float)p * s);
        }
        out[(size_t)row * NN + k] = acc;
    }
}

extern "C" void kernel_launch(void* const* d_in, const int* in_sizes, int n_in,
                              void* d_out, int out_size, void* d_ws, size_t ws_size,
                              hipStream_t stream) {
    const float* x = (const float*)d_in[0];
    float* out = (float*)d_out;

    const size_t eA = (size_t)NN * HH;          // 8 MB each for Ae/Ao
    const size_t eC = (size_t)HH * HH;          // 4 MB each for CE/CO
    const size_t need = 2 * eA + 2 * eC + 2 * NN * sizeof(float);

    if (ws_size >= need) {
        signed char* Ae = (signed char*)d_ws;
        signed char* Ao = Ae + eA;
        signed char* CEm = Ao + eA;
        signed char* COm = CEm + eC;
        float* se = (float*)(COm + eC);
        float* so = se + NN;

        prep_i8<<<8192, 256, 0, stream>>>(x, Ae, Ao, CEm, COm, se, so);

        dim3 grid(HH / BN, NN / BM);            // (16, 32) = 512 blocks
        idct_gemm2<<<grid, 256, 0, stream>>>(Ae, Ao, CEm, COm, se, so, out);
    } else {
        idct_naive<<<NN, 256, 0, stream>>>(x, out);
    }
}